// Round 1
// 1518.425 us; speedup vs baseline: 1.1521x; 1.1521x over previous
//
#include <hip/hip_runtime.h>
#include <stdint.h>

// SquaredExpModel: GP log-likelihood + posterior mean on MI355X (gfx950).
// R3: gemm1 software-pipelined (reg prefetch of A+B during MFMA, LDS dbuf,
// 1 barrier/iter) — R2's gemm1 was latency-serialized at 9.2K cyc/iter with
// reg-capped 2 waves/SIMD. LU diag fused into trsm (25->17 launches, diag
// factored redundantly per block, factored diag kept in side buffer D).
// gemm2 split-K 3->6 + same prefetch pattern.

#define NM 10000
#define ND 552
#define NDP 576
#define NKB 313      // k-blocks of 32 (covers 10016, zero-padded)
#define MT1 79       // M tiles of 128 (covers 10112, guarded)
#define SPLITK 3
#define SPLITK2 6

typedef __attribute__((ext_vector_type(8))) short bf16x8;
typedef __attribute__((ext_vector_type(4))) float f32x4;

__device__ __forceinline__ unsigned short f2bf(float f){
  unsigned u = __float_as_uint(f);
  u += 0x7fffu + ((u >> 16) & 1u);
  return (unsigned short)(u >> 16);
}
__device__ __forceinline__ unsigned int pk2(unsigned short a, unsigned short b){
  return (unsigned int)a | ((unsigned int)b << 16);
}

// ---- Build Bt: F^T in [kb][n][32k] bf16, 16B-chunk swizzle q' = (q + (n>>1))&3 ----
__global__ void prep_bt(const float* __restrict__ F, unsigned short* __restrict__ Bt){
  int bid = blockIdx.x;
  int kb = bid % NKB, nb = bid / NKB;
  int t = threadIdx.x;
  int nl = t >> 2, q = t & 3;
  int gn = nb * 64 + nl;
  int k0 = kb * 32 + q * 8;
  float v[8];
  if (gn < ND && (k0 + 8) <= NM){
    const float* p = F + (size_t)gn * NM + k0;
    float4 a = *(const float4*)p;
    float4 b = *(const float4*)(p + 4);
    v[0]=a.x; v[1]=a.y; v[2]=a.z; v[3]=a.w; v[4]=b.x; v[5]=b.y; v[6]=b.z; v[7]=b.w;
  } else {
    #pragma unroll
    for (int i = 0; i < 8; ++i) v[i] = 0.f;
  }
  unsigned short u[8];
  #pragma unroll
  for (int i = 0; i < 8; ++i) u[i] = f2bf(v[i]);
  size_t cidx = ((size_t)kb * NDP + gn) * 4 + ((q + (gn >> 1)) & 3);
  uint4 w;
  w.x = pk2(u[0],u[1]); w.y = pk2(u[2],u[3]); w.z = pk2(u[4],u[5]); w.w = pk2(u[6],u[7]);
  *(uint4*)(Bt + cidx * 8) = w;
}

// ---- r = d_obs - m0 * rowsum(F); rows >= ND get 0 ----
__global__ void rvec(const float* __restrict__ F, const float* __restrict__ dobs,
                     const float* __restrict__ m0p, float* __restrict__ r){
  __shared__ float red[256];
  int i = blockIdx.x;
  int t = threadIdx.x;
  float s = 0.f;
  if (i < ND){
    for (int k = t; k < NM; k += 256) s += F[(size_t)i * NM + k];
  }
  red[t] = s;
  __syncthreads();
  if (t < 64){
    float v = red[t] + red[t+64] + red[t+128] + red[t+192];
    #pragma unroll
    for (int off = 32; off; off >>= 1) v += __shfl_down(v, off);
    if (t == 0){
      if (i < ND) r[i] = dobs[i] - m0p[0] * v;
      else        r[i] = 0.f;
    }
  }
}

// ---- GEMM1: P[m][n] += sum_k sigma^2*exp(ce*D[m][k]) * F[n][k]  (bf16 MFMA) ----
// Pipelined: prefetch A(fp32)+B(bf16) for kb+1 into regs before MFMA(kb),
// exp/pack/store after MFMA into the other LDS buffer. One barrier per iter.
__global__ __launch_bounds__(512, 2) void gemm1(
    const float* __restrict__ dist, const unsigned short* __restrict__ Bt,
    float* __restrict__ P, const float* __restrict__ lsp, const float* __restrict__ sgp){
  __shared__ unsigned short Alds[2][128 * 40];
  __shared__ unsigned short Blds[2][NDP * 32];
  int bid = blockIdx.x;
  int mtile = bid % MT1, kc = bid / MT1;
  int kb0 = (kc == 0) ? 0 : (105 + 104 * (kc - 1));
  int kbe = kb0 + ((kc == 0) ? 105 : 104);
  int m0 = mtile * 128;
  float ls = lsp[0], sg = sgp[0];
  float ce = -0.72134752044f / (ls * ls);  // -(log2 e)/(2 l^2)
  float s2 = sg * sg;
  int t = threadIdx.x, lane = t & 63, w = t >> 6;
  int wm = w & 1, wn = w >> 1;
  int c16 = lane & 15, q2 = lane >> 4;
  f32x4 acc[4][9];
  #pragma unroll
  for (int a = 0; a < 4; ++a)
    #pragma unroll
    for (int b = 0; b < 9; ++b) acc[a][b] = (f32x4){0.f, 0.f, 0.f, 0.f};

  int rr = t >> 2, qa = t & 3;
  const int arow = (wm * 64 + c16) * 40 + q2 * 8;
  int gm = m0 + rr;
  const float* arow_p = dist + (size_t)gm * NM;

  float av[8];
  uint4 bv[4];
  uint4 btl;
  bool aok = false;

#define G1_ISSUE(KB) { \
    int k0_ = (KB) * 32 + qa * 8; \
    aok = (gm < NM) && (k0_ + 8 <= NM); \
    if (aok){ \
      const float4* p_ = (const float4*)(arow_p + k0_); \
      float4 x_ = p_[0]; float4 y_ = p_[1]; \
      av[0]=x_.x; av[1]=x_.y; av[2]=x_.z; av[3]=x_.w; \
      av[4]=y_.x; av[5]=y_.y; av[6]=y_.z; av[7]=y_.w; \
    } \
    const uint4* bs_ = (const uint4*)Bt + (size_t)(KB) * NDP * 4; \
    bv[0] = bs_[t]; bv[1] = bs_[t + 512]; bv[2] = bs_[t + 1024]; bv[3] = bs_[t + 1536]; \
    if (t < 256) btl = bs_[t + 2048]; \
  }

#define G1_STORE(BUF) { \
    unsigned short u_[8]; \
    if (aok){ \
      _Pragma("unroll") \
      for (int i_ = 0; i_ < 8; ++i_) u_[i_] = f2bf(s2 * exp2f(av[i_] * ce)); \
    } else { \
      _Pragma("unroll") \
      for (int i_ = 0; i_ < 8; ++i_) u_[i_] = 0; \
    } \
    uint4 wv_; \
    wv_.x = pk2(u_[0],u_[1]); wv_.y = pk2(u_[2],u_[3]); \
    wv_.z = pk2(u_[4],u_[5]); wv_.w = pk2(u_[6],u_[7]); \
    *(uint4*)&Alds[BUF][rr * 40 + qa * 8] = wv_; \
    uint4* bd_ = (uint4*)Blds[BUF]; \
    bd_[t] = bv[0]; bd_[t + 512] = bv[1]; bd_[t + 1024] = bv[2]; bd_[t + 1536] = bv[3]; \
    if (t < 256) bd_[t + 2048] = btl; \
  }

  G1_ISSUE(kb0);
  G1_STORE(0);
  __syncthreads();

  for (int kb = kb0; kb < kbe; ++kb){
    int cur = (kb - kb0) & 1;
    if (kb + 1 < kbe) G1_ISSUE(kb + 1);
    bf16x8 af[4];
    #pragma unroll
    for (int mt = 0; mt < 4; ++mt)
      af[mt] = *(const bf16x8*)&Alds[cur][arow + mt * 16 * 40];
    #pragma unroll
    for (int nt = 0; nt < 9; ++nt){
      int n = wn * 144 + nt * 16 + c16;
      int cidx = n * 4 + ((q2 + (n >> 1)) & 3);
      bf16x8 bfv = *(const bf16x8*)&Blds[cur][cidx * 8];
      #pragma unroll
      for (int mt = 0; mt < 4; ++mt)
        acc[mt][nt] = __builtin_amdgcn_mfma_f32_16x16x32_bf16(af[mt], bfv, acc[mt][nt], 0, 0, 0);
    }
    if (kb + 1 < kbe) G1_STORE(cur ^ 1);
    __syncthreads();
  }
#undef G1_ISSUE
#undef G1_STORE

  #pragma unroll
  for (int mt = 0; mt < 4; ++mt)
    #pragma unroll
    for (int nt = 0; nt < 9; ++nt)
      #pragma unroll
      for (int e = 0; e < 4; ++e){
        int gmo = m0 + wm * 64 + mt * 16 + q2 * 4 + e;
        int gno = wn * 144 + nt * 16 + c16;
        if (gmo < NM) atomicAdd(&P[(size_t)gmo * NDP + gno], acc[mt][nt][e]);
      }
}

// ---- Convert P (fp32 [k][n]) -> Pb bf16 swizzled tiles [kb][n][32k] ----
__global__ void conv_p(const float* __restrict__ P, unsigned short* __restrict__ Pb){
  int bid = blockIdx.x;
  int kb = bid % NKB, nb = bid / NKB;
  int t = threadIdx.x;
  int nl = t & 63, q = t >> 6;
  int gn = nb * 64 + nl;
  int k0 = kb * 32 + q * 8;
  unsigned short u[8];
  #pragma unroll
  for (int j = 0; j < 8; ++j){
    int k = k0 + j;
    float v = (k < NM) ? P[(size_t)k * NDP + gn] : 0.f;
    u[j] = f2bf(v);
  }
  size_t cidx = ((size_t)kb * NDP + gn) * 4 + ((q + (gn >> 1)) & 3);
  uint4 w;
  w.x = pk2(u[0],u[1]); w.y = pk2(u[2],u[3]); w.z = pk2(u[4],u[5]); w.w = pk2(u[6],u[7]);
  *(uint4*)(Pb + cidx * 8) = w;
}

// ---- A init ----
__global__ void a_init(const float* __restrict__ dcov, float* __restrict__ A){
  int idx = blockIdx.x * 256 + threadIdx.x;
  if (idx >= NDP * NDP) return;
  int i = idx / NDP, j = idx % NDP;
  float v;
  if (i < ND && j < ND) v = dcov[i * ND + j];
  else v = (i == j) ? 1.f : 0.f;
  A[idx] = v;
}

// ---- GEMM2: A += F @ P  (pipelined, split-K 6) ----
__global__ __launch_bounds__(256) void gemm2(
    const unsigned short* __restrict__ Bt, const unsigned short* __restrict__ Pb,
    float* __restrict__ A){
  __shared__ unsigned short Fa[2][64 * 32];
  __shared__ unsigned short Pl[2][64 * 32];
  int bid = blockIdx.x;
  int tile = bid % 81, kc = bid / 81;
  int ti = tile / 9, tj = tile % 9;
  int i0 = ti * 64, j0 = tj * 64;
  int kb0 = (kc == 0) ? 0 : (53 + 52 * (kc - 1));
  int kbe = kb0 + ((kc == 0) ? 53 : 52);
  int t = threadIdx.x, lane = t & 63, w = t >> 6;
  int wm = w & 1, wn = w >> 1;
  int c16 = lane & 15, q2 = lane >> 4;
  f32x4 acc[2][2];
  #pragma unroll
  for (int a = 0; a < 2; ++a)
    #pragma unroll
    for (int b = 0; b < 2; ++b) acc[a][b] = (f32x4){0.f, 0.f, 0.f, 0.f};

  uint4 fv, pv;
  fv = ((const uint4*)Bt)[((size_t)kb0 * NDP + i0) * 4 + t];
  pv = ((const uint4*)Pb)[((size_t)kb0 * NDP + j0) * 4 + t];
  ((uint4*)Fa[0])[t] = fv;
  ((uint4*)Pl[0])[t] = pv;
  __syncthreads();

  for (int kb = kb0; kb < kbe; ++kb){
    int cur = (kb - kb0) & 1;
    if (kb + 1 < kbe){
      fv = ((const uint4*)Bt)[((size_t)(kb + 1) * NDP + i0) * 4 + t];
      pv = ((const uint4*)Pb)[((size_t)(kb + 1) * NDP + j0) * 4 + t];
    }
    bf16x8 af[2], bfv[2];
    #pragma unroll
    for (int mt = 0; mt < 2; ++mt){
      int il = wm * 32 + mt * 16 + c16;
      af[mt] = *(const bf16x8*)&Fa[cur][(il * 4 + ((q2 + (il >> 1)) & 3)) * 8];
    }
    #pragma unroll
    for (int nt = 0; nt < 2; ++nt){
      int jl = wn * 32 + nt * 16 + c16;
      bfv[nt] = *(const bf16x8*)&Pl[cur][(jl * 4 + ((q2 + (jl >> 1)) & 3)) * 8];
    }
    #pragma unroll
    for (int mt = 0; mt < 2; ++mt)
      #pragma unroll
      for (int nt = 0; nt < 2; ++nt)
        acc[mt][nt] = __builtin_amdgcn_mfma_f32_16x16x32_bf16(af[mt], bfv[nt], acc[mt][nt], 0, 0, 0);
    if (kb + 1 < kbe){
      ((uint4*)Fa[cur ^ 1])[t] = fv;
      ((uint4*)Pl[cur ^ 1])[t] = pv;
    }
    __syncthreads();
  }
  #pragma unroll
  for (int mt = 0; mt < 2; ++mt)
    #pragma unroll
    for (int nt = 0; nt < 2; ++nt)
      #pragma unroll
      for (int e = 0; e < 4; ++e){
        int gi = i0 + wm * 32 + mt * 16 + q2 * 4 + e;
        int gj = j0 + wn * 32 + nt * 16 + c16;
        atomicAdd(&A[(size_t)gi * NDP + gj], acc[mt][nt][e]);
      }
}

// ---- LU (no pivoting), blocked nb=64. Diag factorization fused into trsm:
// every block factors the raw diag in-register (redundant, deterministic);
// block 2*nch writes the factored diag to side buffer D (A keeps raw diag).
__global__ __launch_bounds__(256) void lu_trsm(float* __restrict__ A,
                                               float* __restrict__ D, int k0){
  __shared__ float Dg[64 * 65];
  __shared__ float Tg[64 * 65];
  int t = threadIdx.x;
  int nch = (NDP - k0 - 64) >> 6;
  int bid = blockIdx.x;
  bool writer = (bid == 2 * nch);
  bool isU = bid < nch;
  int ch = isU ? bid : bid - nch;
  int c0 = k0 + 64 + ch * 64;
  int rbase = isU ? k0 : c0;
  int cbase = isU ? c0 : k0;
  for (int fid = t; fid < 1024; fid += 256){
    int row = fid >> 4, c4 = (fid & 15) << 2;
    float4 v = *(const float4*)&A[(size_t)(k0 + row) * NDP + k0 + c4];
    Dg[row * 65 + c4 + 0] = v.x; Dg[row * 65 + c4 + 1] = v.y;
    Dg[row * 65 + c4 + 2] = v.z; Dg[row * 65 + c4 + 3] = v.w;
  }
  if (!writer){
    for (int fid = t; fid < 1024; fid += 256){
      int row = fid >> 4, c4 = (fid & 15) << 2;
      float4 v = *(const float4*)&A[(size_t)(rbase + row) * NDP + cbase + c4];
      Tg[row * 65 + c4 + 0] = v.x; Tg[row * 65 + c4 + 1] = v.y;
      Tg[row * 65 + c4 + 2] = v.z; Tg[row * 65 + c4 + 3] = v.w;
    }
  }
  __syncthreads();
  // in-register 64x64 LU of the diag block (wave 0)
  if (t < 64){
    int l = t;
    float rg[64];
    #pragma unroll
    for (int c = 0; c < 64; ++c) rg[c] = Dg[l * 65 + c];
    #pragma unroll
    for (int j = 0; j < 64; ++j){
      float piv = __shfl(rg[j], j);
      float lij = rg[j] / piv;
      float m = (l > j) ? 1.f : 0.f;
      float mlij = m * lij;
      #pragma unroll
      for (int c = j + 1; c < 64; ++c){
        float rjc = __shfl(rg[c], j);
        rg[c] -= mlij * rjc;
      }
      if (l > j) rg[j] = lij;
    }
    #pragma unroll
    for (int c = 0; c < 64; ++c) Dg[l * 65 + c] = rg[c];
  }
  __syncthreads();
  if (writer){
    float* dd = D + (size_t)(k0 >> 6) * 4096;
    for (int fid = t; fid < 1024; fid += 256){
      int row = fid >> 4, c4 = (fid & 15) << 2;
      float4 v;
      v.x = Dg[row * 65 + c4 + 0]; v.y = Dg[row * 65 + c4 + 1];
      v.z = Dg[row * 65 + c4 + 2]; v.w = Dg[row * 65 + c4 + 3];
      *(float4*)&dd[row * 64 + c4] = v;
    }
    return;
  }
  if (t < 64){
    if (isU){
      // solve L X = T; lane owns column t
      float x[64];
      #pragma unroll
      for (int i = 0; i < 64; ++i) x[i] = Tg[i * 65 + t];
      #pragma unroll
      for (int i = 0; i < 64; ++i){
        #pragma unroll
        for (int ii = i + 1; ii < 64; ++ii)
          x[ii] -= Dg[ii * 65 + i] * x[i];
      }
      #pragma unroll
      for (int i = 0; i < 64; ++i) Tg[i * 65 + t] = x[i];
    } else {
      // solve X U = T; lane owns row t
      float x[64];
      #pragma unroll
      for (int j = 0; j < 64; ++j) x[j] = Tg[t * 65 + j];
      #pragma unroll
      for (int j = 0; j < 64; ++j){
        x[j] /= Dg[j * 65 + j];
        #pragma unroll
        for (int jj = j + 1; jj < 64; ++jj)
          x[jj] -= x[j] * Dg[j * 65 + jj];
      }
      #pragma unroll
      for (int j = 0; j < 64; ++j) Tg[t * 65 + j] = x[j];
    }
  }
  __syncthreads();
  for (int fid = t; fid < 1024; fid += 256){
    int row = fid >> 4, c4 = (fid & 15) << 2;
    float4 v;
    v.x = Tg[row * 65 + c4 + 0]; v.y = Tg[row * 65 + c4 + 1];
    v.z = Tg[row * 65 + c4 + 2]; v.w = Tg[row * 65 + c4 + 3];
    *(float4*)&A[(size_t)(rbase + row) * NDP + cbase + c4] = v;
  }
}

__global__ __launch_bounds__(256) void lu_gemmk(float* __restrict__ A, int k0){
  __shared__ float Lt[32 * 65];
  __shared__ float Ut[64 * 33];
  int n2 = NDP - k0 - 64;
  int nb = n2 >> 5;
  int bx = blockIdx.x % nb, by = blockIdx.x / nb;
  int r0 = k0 + 64 + bx * 32, c0 = k0 + 64 + by * 32;
  int t = threadIdx.x;
  for (int idx = t; idx < 2048; idx += 256){
    int i = idx >> 6, kk = idx & 63;
    Lt[i * 65 + kk] = A[(size_t)(r0 + i) * NDP + k0 + kk];
  }
  for (int idx = t; idx < 2048; idx += 256){
    int kk = idx >> 5, j = idx & 31;
    Ut[kk * 33 + j] = A[(size_t)(k0 + kk) * NDP + c0 + j];
  }
  __syncthreads();
  int i = t >> 3, j4 = (t & 7) * 4;
  float acc[4] = {0.f, 0.f, 0.f, 0.f};
  for (int kk = 0; kk < 64; ++kk){
    float lv = Lt[i * 65 + kk];
    #pragma unroll
    for (int u = 0; u < 4; ++u) acc[u] += lv * Ut[kk * 33 + j4 + u];
  }
  float* dst = &A[(size_t)(r0 + i) * NDP + c0 + j4];
  #pragma unroll
  for (int u = 0; u < 4; ++u) dst[u] -= acc[u];
}

// ---- Parallel solve: 576 threads, thread i owns row i.
// Diag blocks come from side buffer D (A's diag blocks stay unfactored).
__global__ __launch_bounds__(576) void solve_ll(
    const float* __restrict__ A, const float* __restrict__ D,
    const float* __restrict__ r, float* __restrict__ tmp, float* __restrict__ out0){
  __shared__ float ys[NDP];
  __shared__ float red[16];
  int t = threadIdx.x;
  int w = t >> 6, l = t & 63;
  int i = t;
  float y = r[i];
  float rsave = y;
  float ldpart = 0.f;
  float row[64];

  // ---- forward: L y' = r ----
  for (int jb = 0; jb < 9; ++jb){
    if (w == jb){
      const float4* ap = (const float4*)(D + (size_t)jb * 4096 + (size_t)l * 64);
      #pragma unroll
      for (int q = 0; q < 16; ++q) ((float4*)row)[q] = ap[q];
    } else if (w > jb){
      const float4* ap = (const float4*)(A + (size_t)i * NDP + jb * 64);
      #pragma unroll
      for (int q = 0; q < 16; ++q) ((float4*)row)[q] = ap[q];
    }
    if (w == jb){
      #pragma unroll
      for (int j = 0; j < 64; ++j){
        float yj = __shfl(y, j);
        if (l > j) y -= row[j] * yj;
      }
      ys[i] = y;
    }
    __syncthreads();
    if (w > jb){
      #pragma unroll
      for (int j = 0; j < 64; ++j) y -= row[j] * ys[jb * 64 + j];
    }
  }
  __syncthreads();

  // ---- backward: U y = y' ----
  for (int jb = 8; jb >= 0; --jb){
    if (w == jb){
      const float4* ap = (const float4*)(D + (size_t)jb * 4096 + (size_t)l * 64);
      #pragma unroll
      for (int q = 0; q < 16; ++q) ((float4*)row)[q] = ap[q];
    } else if (w < jb){
      const float4* ap = (const float4*)(A + (size_t)i * NDP + jb * 64);
      #pragma unroll
      for (int q = 0; q < 16; ++q) ((float4*)row)[q] = ap[q];
    }
    if (w == jb){
      float dv = D[(size_t)jb * 4096 + (size_t)l * 64 + l];   // own diagonal
      float dinv = 1.f / dv;
      ldpart = logf(fabsf(dv));
      #pragma unroll
      for (int j = 63; j >= 0; --j){
        float yj = __shfl(y, j) * __shfl(dinv, j);
        if (l == j) y = yj;
        if (l < j)  y -= row[j] * yj;
      }
      ys[i] = y;
    }
    __syncthreads();
    if (w < jb){
      #pragma unroll
      for (int j = 0; j < 64; ++j) y -= row[j] * ys[jb * 64 + j];
    }
  }

  tmp[i] = y;
  // out0 = sum(log|U_ii|) + r . y
  float contrib = ldpart + rsave * y;
  #pragma unroll
  for (int off = 32; off; off >>= 1) contrib += __shfl_down(contrib, off);
  if (l == 0) red[w] = contrib;
  __syncthreads();
  if (t == 0){
    float s = 0.f;
    #pragma unroll
    for (int k = 0; k < 9; ++k) s += red[k];
    out0[0] = s;
  }
}

// ---- m_posterior = m0 + P @ tmp ----
__global__ void mpost(const float* __restrict__ P, const float* __restrict__ tmp,
                      const float* __restrict__ m0p, float* __restrict__ out1){
  int w = threadIdx.x >> 6, l = threadIdx.x & 63;
  int m = blockIdx.x * 4 + w;
  if (m >= NM) return;
  float s = 0.f;
  #pragma unroll
  for (int i = 0; i < 9; ++i){
    int n = i * 64 + l;
    s += P[(size_t)m * NDP + n] * tmp[n];
  }
  #pragma unroll
  for (int off = 32; off; off >>= 1) s += __shfl_down(s, off);
  if (l == 0) out1[m] = m0p[0] + s;
}

extern "C" void kernel_launch(void* const* d_in, const int* in_sizes, int n_in,
                              void* d_out, int out_size, void* d_ws, size_t ws_size,
                              hipStream_t stream){
  const float* dist = (const float*)d_in[0];
  const float* F    = (const float*)d_in[1];
  const float* dobs = (const float*)d_in[2];
  const float* dcov = (const float*)d_in[3];
  const float* m0p  = (const float*)d_in[4];
  const float* lsp  = (const float*)d_in[5];
  const float* sgp  = (const float*)d_in[6];
  float* out = (float*)d_out;
  char* ws = (char*)d_ws;

  unsigned short* Bt = (unsigned short*)(ws + 0);
  float*          P  = (float*)(ws + 11538432);
  unsigned short* Pb = (unsigned short*)(ws + 34578432);
  float*          A  = (float*)(ws + 46116864);
  float*          r  = (float*)(ws + 47443968);
  float*          tp = (float*)(ws + 47446272);
  // D (factored diag blocks, 9*64*64 fp32 = 147456 B) aliases Pb: Pb is dead
  // after gemm2, and the first lu_trsm runs strictly after gemm2 in-stream.
  float*          D  = (float*)(ws + 34578432);

  hipMemsetAsync(P, 0, (size_t)NM * NDP * sizeof(float), stream);
  prep_bt<<<NKB * 9, 256, 0, stream>>>(F, Bt);
  rvec<<<NDP, 256, 0, stream>>>(F, dobs, m0p, r);
  gemm1<<<MT1 * SPLITK, 512, 0, stream>>>(dist, Bt, P, lsp, sgp);
  conv_p<<<NKB * 9, 256, 0, stream>>>(P, Pb);
  a_init<<<(NDP * NDP) / 256, 256, 0, stream>>>(dcov, A);
  gemm2<<<81 * SPLITK2, 256, 0, stream>>>(Bt, Pb, A);
  for (int k = 0; k < 9; ++k){
    int nch = 8 - k;
    lu_trsm<<<2 * nch + 1, 256, 0, stream>>>(A, D, k * 64);
    if (k < 8){
      int nb = (NDP - k * 64 - 64) >> 5;
      lu_gemmk<<<nb * nb, 256, 0, stream>>>(A, k * 64);
    }
  }
  solve_ll<<<1, 576, 0, stream>>>(A, D, r, tp, out);
  mpost<<<2500, 256, 0, stream>>>(P, tp, m0p, out + 1);
}

// Round 2
// 1387.296 us; speedup vs baseline: 1.2610x; 1.0945x over previous
//
#include <hip/hip_runtime.h>
#include <stdint.h>

// SquaredExpModel: GP log-likelihood + posterior mean on MI355X (gfx950).
// R4: gemm1 rewritten LDS-free + barrier-free: A and B MFMA fragments loaded
// directly from global into registers (Bt's pre-swizzled layout makes each
// B-fragment one contiguous 16B chunk; A coalesces to 16 rows x 128B lines),
// exp2+pack in-register, per-wave distance-1 prefetch with compiler counted
// vmcnt (no barrier => no vmcnt(0) drain). Tile 64x576, acc 72/lane.
// prep_bt+rvec+a_init fused into one launch.

#define NM 10000
#define ND 552
#define NDP 576
#define NKB 313      // k-blocks of 32 (covers 10016, zero-padded)
#define MT1 157      // M tiles of 64 (covers 10048, guarded)
#define SPLITK 3
#define SPLITK2 6

#define PREP_BT_BLOCKS (NKB * 9)          // 2817
#define RVEC_BLOCKS    NDP                // 576
#define AINIT_BLOCKS   ((NDP * NDP) / 256)  // 1296

typedef __attribute__((ext_vector_type(8))) short bf16x8;
typedef __attribute__((ext_vector_type(4))) float f32x4;

__device__ __forceinline__ unsigned short f2bf(float f){
  unsigned u = __float_as_uint(f);
  u += 0x7fffu + ((u >> 16) & 1u);
  return (unsigned short)(u >> 16);
}
__device__ __forceinline__ unsigned int pk2(unsigned short a, unsigned short b){
  return (unsigned int)a | ((unsigned int)b << 16);
}

// ---- Fused prologue: prep_bt | rvec | a_init (independent, range-dispatch) ----
__global__ void prep_fused(const float* __restrict__ F, const float* __restrict__ dobs,
                           const float* __restrict__ m0p, const float* __restrict__ dcov,
                           unsigned short* __restrict__ Bt, float* __restrict__ r,
                           float* __restrict__ A){
  __shared__ float red[256];
  int b = blockIdx.x;
  int t = threadIdx.x;
  if (b < PREP_BT_BLOCKS){
    // Build Bt: F^T in [kb][n][32k] bf16, 16B-chunk swizzle q' = (q + (n>>1))&3
    int kb = b % NKB, nb = b / NKB;
    int nl = t >> 2, q = t & 3;
    int gn = nb * 64 + nl;
    int k0 = kb * 32 + q * 8;
    float v[8];
    if (gn < ND && (k0 + 8) <= NM){
      const float* p = F + (size_t)gn * NM + k0;
      float4 a = *(const float4*)p;
      float4 bb = *(const float4*)(p + 4);
      v[0]=a.x; v[1]=a.y; v[2]=a.z; v[3]=a.w; v[4]=bb.x; v[5]=bb.y; v[6]=bb.z; v[7]=bb.w;
    } else {
      #pragma unroll
      for (int i = 0; i < 8; ++i) v[i] = 0.f;
    }
    unsigned short u[8];
    #pragma unroll
    for (int i = 0; i < 8; ++i) u[i] = f2bf(v[i]);
    size_t cidx = ((size_t)kb * NDP + gn) * 4 + ((q + (gn >> 1)) & 3);
    uint4 w;
    w.x = pk2(u[0],u[1]); w.y = pk2(u[2],u[3]); w.z = pk2(u[4],u[5]); w.w = pk2(u[6],u[7]);
    *(uint4*)(Bt + cidx * 8) = w;
  } else if (b < PREP_BT_BLOCKS + RVEC_BLOCKS){
    // r = d_obs - m0 * rowsum(F); rows >= ND get 0
    int i = b - PREP_BT_BLOCKS;
    float s = 0.f;
    if (i < ND){
      for (int k = t; k < NM; k += 256) s += F[(size_t)i * NM + k];
    }
    red[t] = s;
    __syncthreads();
    if (t < 64){
      float v = red[t] + red[t+64] + red[t+128] + red[t+192];
      #pragma unroll
      for (int off = 32; off; off >>= 1) v += __shfl_down(v, off);
      if (t == 0){
        if (i < ND) r[i] = dobs[i] - m0p[0] * v;
        else        r[i] = 0.f;
      }
    }
  } else {
    int idx = (b - PREP_BT_BLOCKS - RVEC_BLOCKS) * 256 + t;
    if (idx < NDP * NDP){
      int i = idx / NDP, j = idx % NDP;
      float v;
      if (i < ND && j < ND) v = dcov[i * ND + j];
      else v = (i == j) ? 1.f : 0.f;
      A[idx] = v;
    }
  }
}

// ---- GEMM1: P[m][n] += sum_k sigma^2*exp(ce*D[m][k]) * F[n][k]  (bf16 MFMA) ----
// LDS-free, barrier-free: direct per-fragment global loads, in-register
// exp2+pack, per-wave distance-1 register prefetch (ping-pong A/B sets).
__global__ __launch_bounds__(512, 2) void gemm1(
    const float* __restrict__ dist, const unsigned short* __restrict__ Bt,
    float* __restrict__ P, const float* __restrict__ lsp, const float* __restrict__ sgp){
  int bid = blockIdx.x;
  int mtile = bid % MT1, kc = bid / MT1;
  int kb0 = (kc == 0) ? 0 : (105 + 104 * (kc - 1));
  int kbe = kb0 + ((kc == 0) ? 105 : 104);
  int m0 = mtile * 64;
  float ls = lsp[0], sg = sgp[0];
  float ce = -0.72134752044f / (ls * ls);  // -(log2 e)/(2 l^2)
  float s2 = sg * sg;
  int t = threadIdx.x, lane = t & 63, w = t >> 6;
  int wm = w & 1, wn = w >> 1;
  int c16 = lane & 15, q2 = lane >> 4;

  // A row pointers for mt=0,1 (row = m0 + wm*32 + mt*16 + c16); clamp OOB rows
  int r0 = m0 + wm * 32 + c16;
  int r1 = r0 + 16;
  const float* pa0 = dist + (size_t)(r0 < NM ? r0 : NM - 1) * NM;
  const float* pa1 = dist + (size_t)(r1 < NM ? r1 : NM - 1) * NM;
  int koff = q2 * 8;

  // B fragment byte offsets within a kb slice (lane-constant across kb)
  const char* pbbase = (const char*)Bt;
  int boff[9];
  #pragma unroll
  for (int nt = 0; nt < 9; ++nt){
    int n = wn * 144 + nt * 16 + c16;
    boff[nt] = (n * 4 + ((q2 + (n >> 1)) & 3)) * 16;
  }

  f32x4 acc[2][9];
  #pragma unroll
  for (int a = 0; a < 2; ++a)
    #pragma unroll
    for (int bq = 0; bq < 9; ++bq) acc[a][bq] = (f32x4){0.f, 0.f, 0.f, 0.f};

  float4 avA[4], avB[4];
  bf16x8 bfA[9], bfB[9];
  bool okA = false, okB = false;

#define G1_ISSUE(SET, KB) { \
    int k0_ = (KB) * 32 + koff; \
    ok##SET = (k0_ + 8 <= NM); \
    if (ok##SET){ \
      const float4* a0_ = (const float4*)(pa0 + k0_); \
      const float4* a1_ = (const float4*)(pa1 + k0_); \
      av##SET[0] = a0_[0]; av##SET[1] = a0_[1]; \
      av##SET[2] = a1_[0]; av##SET[3] = a1_[1]; \
    } \
    const char* bs_ = pbbase + (size_t)(KB) * (NDP * 32 * 2); \
    _Pragma("unroll") \
    for (int nt_ = 0; nt_ < 9; ++nt_) \
      bf##SET[nt_] = *(const bf16x8*)(bs_ + boff[nt_]); \
  }

#define G1_CONSUME(SET) { \
    unsigned short u_[16]; \
    if (ok##SET){ \
      float vv_[16]; \
      vv_[0]=av##SET[0].x; vv_[1]=av##SET[0].y; vv_[2]=av##SET[0].z; vv_[3]=av##SET[0].w; \
      vv_[4]=av##SET[1].x; vv_[5]=av##SET[1].y; vv_[6]=av##SET[1].z; vv_[7]=av##SET[1].w; \
      vv_[8]=av##SET[2].x; vv_[9]=av##SET[2].y; vv_[10]=av##SET[2].z; vv_[11]=av##SET[2].w; \
      vv_[12]=av##SET[3].x; vv_[13]=av##SET[3].y; vv_[14]=av##SET[3].z; vv_[15]=av##SET[3].w; \
      _Pragma("unroll") \
      for (int i_ = 0; i_ < 16; ++i_) u_[i_] = f2bf(s2 * exp2f(vv_[i_] * ce)); \
    } else { \
      _Pragma("unroll") \
      for (int i_ = 0; i_ < 16; ++i_) u_[i_] = 0; \
    } \
    bf16x8 af0_, af1_; \
    _Pragma("unroll") \
    for (int i_ = 0; i_ < 8; ++i_){ af0_[i_] = (short)u_[i_]; af1_[i_] = (short)u_[i_ + 8]; } \
    _Pragma("unroll") \
    for (int nt_ = 0; nt_ < 9; ++nt_){ \
      acc[0][nt_] = __builtin_amdgcn_mfma_f32_16x16x32_bf16(af0_, bf##SET[nt_], acc[0][nt_], 0, 0, 0); \
      acc[1][nt_] = __builtin_amdgcn_mfma_f32_16x16x32_bf16(af1_, bf##SET[nt_], acc[1][nt_], 0, 0, 0); \
    } \
  }

  G1_ISSUE(A, kb0);
  for (int kb = kb0; kb < kbe; kb += 2){
    if (kb + 1 < kbe) G1_ISSUE(B, kb + 1);
    G1_CONSUME(A);
    if (kb + 1 < kbe){
      if (kb + 2 < kbe) G1_ISSUE(A, kb + 2);
      G1_CONSUME(B);
    }
  }
#undef G1_ISSUE
#undef G1_CONSUME

  #pragma unroll
  for (int mt = 0; mt < 2; ++mt)
    #pragma unroll
    for (int nt = 0; nt < 9; ++nt)
      #pragma unroll
      for (int e = 0; e < 4; ++e){
        int gmo = m0 + wm * 32 + mt * 16 + q2 * 4 + e;
        int gno = wn * 144 + nt * 16 + c16;
        if (gmo < NM) atomicAdd(&P[(size_t)gmo * NDP + gno], acc[mt][nt][e]);
      }
}

// ---- Convert P (fp32 [k][n]) -> Pb bf16 swizzled tiles [kb][n][32k] ----
__global__ void conv_p(const float* __restrict__ P, unsigned short* __restrict__ Pb){
  int bid = blockIdx.x;
  int kb = bid % NKB, nb = bid / NKB;
  int t = threadIdx.x;
  int nl = t & 63, q = t >> 6;
  int gn = nb * 64 + nl;
  int k0 = kb * 32 + q * 8;
  unsigned short u[8];
  #pragma unroll
  for (int j = 0; j < 8; ++j){
    int k = k0 + j;
    float v = (k < NM) ? P[(size_t)k * NDP + gn] : 0.f;
    u[j] = f2bf(v);
  }
  size_t cidx = ((size_t)kb * NDP + gn) * 4 + ((q + (gn >> 1)) & 3);
  uint4 w;
  w.x = pk2(u[0],u[1]); w.y = pk2(u[2],u[3]); w.z = pk2(u[4],u[5]); w.w = pk2(u[6],u[7]);
  *(uint4*)(Pb + cidx * 8) = w;
}

// ---- GEMM2: A += F @ P  (pipelined, split-K 6) ----
__global__ __launch_bounds__(256) void gemm2(
    const unsigned short* __restrict__ Bt, const unsigned short* __restrict__ Pb,
    float* __restrict__ A){
  __shared__ unsigned short Fa[2][64 * 32];
  __shared__ unsigned short Pl[2][64 * 32];
  int bid = blockIdx.x;
  int tile = bid % 81, kc = bid / 81;
  int ti = tile / 9, tj = tile % 9;
  int i0 = ti * 64, j0 = tj * 64;
  int kb0 = (kc == 0) ? 0 : (53 + 52 * (kc - 1));
  int kbe = kb0 + ((kc == 0) ? 53 : 52);
  int t = threadIdx.x, lane = t & 63, w = t >> 6;
  int wm = w & 1, wn = w >> 1;
  int c16 = lane & 15, q2 = lane >> 4;
  f32x4 acc[2][2];
  #pragma unroll
  for (int a = 0; a < 2; ++a)
    #pragma unroll
    for (int b = 0; b < 2; ++b) acc[a][b] = (f32x4){0.f, 0.f, 0.f, 0.f};

  uint4 fv, pv;
  fv = ((const uint4*)Bt)[((size_t)kb0 * NDP + i0) * 4 + t];
  pv = ((const uint4*)Pb)[((size_t)kb0 * NDP + j0) * 4 + t];
  ((uint4*)Fa[0])[t] = fv;
  ((uint4*)Pl[0])[t] = pv;
  __syncthreads();

  for (int kb = kb0; kb < kbe; ++kb){
    int cur = (kb - kb0) & 1;
    if (kb + 1 < kbe){
      fv = ((const uint4*)Bt)[((size_t)(kb + 1) * NDP + i0) * 4 + t];
      pv = ((const uint4*)Pb)[((size_t)(kb + 1) * NDP + j0) * 4 + t];
    }
    bf16x8 af[2], bfv[2];
    #pragma unroll
    for (int mt = 0; mt < 2; ++mt){
      int il = wm * 32 + mt * 16 + c16;
      af[mt] = *(const bf16x8*)&Fa[cur][(il * 4 + ((q2 + (il >> 1)) & 3)) * 8];
    }
    #pragma unroll
    for (int nt = 0; nt < 2; ++nt){
      int jl = wn * 32 + nt * 16 + c16;
      bfv[nt] = *(const bf16x8*)&Pl[cur][(jl * 4 + ((q2 + (jl >> 1)) & 3)) * 8];
    }
    #pragma unroll
    for (int mt = 0; mt < 2; ++mt)
      #pragma unroll
      for (int nt = 0; nt < 2; ++nt)
        acc[mt][nt] = __builtin_amdgcn_mfma_f32_16x16x32_bf16(af[mt], bfv[nt], acc[mt][nt], 0, 0, 0);
    if (kb + 1 < kbe){
      ((uint4*)Fa[cur ^ 1])[t] = fv;
      ((uint4*)Pl[cur ^ 1])[t] = pv;
    }
    __syncthreads();
  }
  #pragma unroll
  for (int mt = 0; mt < 2; ++mt)
    #pragma unroll
    for (int nt = 0; nt < 2; ++nt)
      #pragma unroll
      for (int e = 0; e < 4; ++e){
        int gi = i0 + wm * 32 + mt * 16 + q2 * 4 + e;
        int gj = j0 + wn * 32 + nt * 16 + c16;
        atomicAdd(&A[(size_t)gi * NDP + gj], acc[mt][nt][e]);
      }
}

// ---- LU (no pivoting), blocked nb=64. Diag factorization fused into trsm:
// every block factors the raw diag in-register (redundant, deterministic);
// block 2*nch writes the factored diag to side buffer D (A keeps raw diag).
__global__ __launch_bounds__(256) void lu_trsm(float* __restrict__ A,
                                               float* __restrict__ D, int k0){
  __shared__ float Dg[64 * 65];
  __shared__ float Tg[64 * 65];
  int t = threadIdx.x;
  int nch = (NDP - k0 - 64) >> 6;
  int bid = blockIdx.x;
  bool writer = (bid == 2 * nch);
  bool isU = bid < nch;
  int ch = isU ? bid : bid - nch;
  int c0 = k0 + 64 + ch * 64;
  int rbase = isU ? k0 : c0;
  int cbase = isU ? c0 : k0;
  for (int fid = t; fid < 1024; fid += 256){
    int row = fid >> 4, c4 = (fid & 15) << 2;
    float4 v = *(const float4*)&A[(size_t)(k0 + row) * NDP + k0 + c4];
    Dg[row * 65 + c4 + 0] = v.x; Dg[row * 65 + c4 + 1] = v.y;
    Dg[row * 65 + c4 + 2] = v.z; Dg[row * 65 + c4 + 3] = v.w;
  }
  if (!writer){
    for (int fid = t; fid < 1024; fid += 256){
      int row = fid >> 4, c4 = (fid & 15) << 2;
      float4 v = *(const float4*)&A[(size_t)(rbase + row) * NDP + cbase + c4];
      Tg[row * 65 + c4 + 0] = v.x; Tg[row * 65 + c4 + 1] = v.y;
      Tg[row * 65 + c4 + 2] = v.z; Tg[row * 65 + c4 + 3] = v.w;
    }
  }
  __syncthreads();
  // in-register 64x64 LU of the diag block (wave 0)
  if (t < 64){
    int l = t;
    float rg[64];
    #pragma unroll
    for (int c = 0; c < 64; ++c) rg[c] = Dg[l * 65 + c];
    #pragma unroll
    for (int j = 0; j < 64; ++j){
      float piv = __shfl(rg[j], j);
      float lij = rg[j] / piv;
      float m = (l > j) ? 1.f : 0.f;
      float mlij = m * lij;
      #pragma unroll
      for (int c = j + 1; c < 64; ++c){
        float rjc = __shfl(rg[c], j);
        rg[c] -= mlij * rjc;
      }
      if (l > j) rg[j] = lij;
    }
    #pragma unroll
    for (int c = 0; c < 64; ++c) Dg[l * 65 + c] = rg[c];
  }
  __syncthreads();
  if (writer){
    float* dd = D + (size_t)(k0 >> 6) * 4096;
    for (int fid = t; fid < 1024; fid += 256){
      int row = fid >> 4, c4 = (fid & 15) << 2;
      float4 v;
      v.x = Dg[row * 65 + c4 + 0]; v.y = Dg[row * 65 + c4 + 1];
      v.z = Dg[row * 65 + c4 + 2]; v.w = Dg[row * 65 + c4 + 3];
      *(float4*)&dd[row * 64 + c4] = v;
    }
    return;
  }
  if (t < 64){
    if (isU){
      // solve L X = T; lane owns column t
      float x[64];
      #pragma unroll
      for (int i = 0; i < 64; ++i) x[i] = Tg[i * 65 + t];
      #pragma unroll
      for (int i = 0; i < 64; ++i){
        #pragma unroll
        for (int ii = i + 1; ii < 64; ++ii)
          x[ii] -= Dg[ii * 65 + i] * x[i];
      }
      #pragma unroll
      for (int i = 0; i < 64; ++i) Tg[i * 65 + t] = x[i];
    } else {
      // solve X U = T; lane owns row t
      float x[64];
      #pragma unroll
      for (int j = 0; j < 64; ++j) x[j] = Tg[t * 65 + j];
      #pragma unroll
      for (int j = 0; j < 64; ++j){
        x[j] /= Dg[j * 65 + j];
        #pragma unroll
        for (int jj = j + 1; jj < 64; ++jj)
          x[jj] -= x[j] * Dg[j * 65 + jj];
      }
      #pragma unroll
      for (int j = 0; j < 64; ++j) Tg[t * 65 + j] = x[j];
    }
  }
  __syncthreads();
  for (int fid = t; fid < 1024; fid += 256){
    int row = fid >> 4, c4 = (fid & 15) << 2;
    float4 v;
    v.x = Tg[row * 65 + c4 + 0]; v.y = Tg[row * 65 + c4 + 1];
    v.z = Tg[row * 65 + c4 + 2]; v.w = Tg[row * 65 + c4 + 3];
    *(float4*)&A[(size_t)(rbase + row) * NDP + cbase + c4] = v;
  }
}

__global__ __launch_bounds__(256) void lu_gemmk(float* __restrict__ A, int k0){
  __shared__ float Lt[32 * 65];
  __shared__ float Ut[64 * 33];
  int n2 = NDP - k0 - 64;
  int nb = n2 >> 5;
  int bx = blockIdx.x % nb, by = blockIdx.x / nb;
  int r0 = k0 + 64 + bx * 32, c0 = k0 + 64 + by * 32;
  int t = threadIdx.x;
  for (int idx = t; idx < 2048; idx += 256){
    int i = idx >> 6, kk = idx & 63;
    Lt[i * 65 + kk] = A[(size_t)(r0 + i) * NDP + k0 + kk];
  }
  for (int idx = t; idx < 2048; idx += 256){
    int kk = idx >> 5, j = idx & 31;
    Ut[kk * 33 + j] = A[(size_t)(k0 + kk) * NDP + c0 + j];
  }
  __syncthreads();
  int i = t >> 3, j4 = (t & 7) * 4;
  float acc[4] = {0.f, 0.f, 0.f, 0.f};
  for (int kk = 0; kk < 64; ++kk){
    float lv = Lt[i * 65 + kk];
    #pragma unroll
    for (int u = 0; u < 4; ++u) acc[u] += lv * Ut[kk * 33 + j4 + u];
  }
  float* dst = &A[(size_t)(r0 + i) * NDP + c0 + j4];
  #pragma unroll
  for (int u = 0; u < 4; ++u) dst[u] -= acc[u];
}

// ---- Parallel solve: 576 threads, thread i owns row i.
// Diag blocks come from side buffer D (A's diag blocks stay unfactored).
__global__ __launch_bounds__(576) void solve_ll(
    const float* __restrict__ A, const float* __restrict__ D,
    const float* __restrict__ r, float* __restrict__ tmp, float* __restrict__ out0){
  __shared__ float ys[NDP];
  __shared__ float red[16];
  int t = threadIdx.x;
  int w = t >> 6, l = t & 63;
  int i = t;
  float y = r[i];
  float rsave = y;
  float ldpart = 0.f;
  float row[64];

  // ---- forward: L y' = r ----
  for (int jb = 0; jb < 9; ++jb){
    if (w == jb){
      const float4* ap = (const float4*)(D + (size_t)jb * 4096 + (size_t)l * 64);
      #pragma unroll
      for (int q = 0; q < 16; ++q) ((float4*)row)[q] = ap[q];
    } else if (w > jb){
      const float4* ap = (const float4*)(A + (size_t)i * NDP + jb * 64);
      #pragma unroll
      for (int q = 0; q < 16; ++q) ((float4*)row)[q] = ap[q];
    }
    if (w == jb){
      #pragma unroll
      for (int j = 0; j < 64; ++j){
        float yj = __shfl(y, j);
        if (l > j) y -= row[j] * yj;
      }
      ys[i] = y;
    }
    __syncthreads();
    if (w > jb){
      #pragma unroll
      for (int j = 0; j < 64; ++j) y -= row[j] * ys[jb * 64 + j];
    }
  }
  __syncthreads();

  // ---- backward: U y = y' ----
  for (int jb = 8; jb >= 0; --jb){
    if (w == jb){
      const float4* ap = (const float4*)(D + (size_t)jb * 4096 + (size_t)l * 64);
      #pragma unroll
      for (int q = 0; q < 16; ++q) ((float4*)row)[q] = ap[q];
    } else if (w < jb){
      const float4* ap = (const float4*)(A + (size_t)i * NDP + jb * 64);
      #pragma unroll
      for (int q = 0; q < 16; ++q) ((float4*)row)[q] = ap[q];
    }
    if (w == jb){
      float dv = D[(size_t)jb * 4096 + (size_t)l * 64 + l];   // own diagonal
      float dinv = 1.f / dv;
      ldpart = logf(fabsf(dv));
      #pragma unroll
      for (int j = 63; j >= 0; --j){
        float yj = __shfl(y, j) * __shfl(dinv, j);
        if (l == j) y = yj;
        if (l < j)  y -= row[j] * yj;
      }
      ys[i] = y;
    }
    __syncthreads();
    if (w < jb){
      #pragma unroll
      for (int j = 0; j < 64; ++j) y -= row[j] * ys[jb * 64 + j];
    }
  }

  tmp[i] = y;
  // out0 = sum(log|U_ii|) + r . y
  float contrib = ldpart + rsave * y;
  #pragma unroll
  for (int off = 32; off; off >>= 1) contrib += __shfl_down(contrib, off);
  if (l == 0) red[w] = contrib;
  __syncthreads();
  if (t == 0){
    float s = 0.f;
    #pragma unroll
    for (int k = 0; k < 9; ++k) s += red[k];
    out0[0] = s;
  }
}

// ---- m_posterior = m0 + P @ tmp ----
__global__ void mpost(const float* __restrict__ P, const float* __restrict__ tmp,
                      const float* __restrict__ m0p, float* __restrict__ out1){
  int w = threadIdx.x >> 6, l = threadIdx.x & 63;
  int m = blockIdx.x * 4 + w;
  if (m >= NM) return;
  float s = 0.f;
  #pragma unroll
  for (int i = 0; i < 9; ++i){
    int n = i * 64 + l;
    s += P[(size_t)m * NDP + n] * tmp[n];
  }
  #pragma unroll
  for (int off = 32; off; off >>= 1) s += __shfl_down(s, off);
  if (l == 0) out1[m] = m0p[0] + s;
}

extern "C" void kernel_launch(void* const* d_in, const int* in_sizes, int n_in,
                              void* d_out, int out_size, void* d_ws, size_t ws_size,
                              hipStream_t stream){
  const float* dist = (const float*)d_in[0];
  const float* F    = (const float*)d_in[1];
  const float* dobs = (const float*)d_in[2];
  const float* dcov = (const float*)d_in[3];
  const float* m0p  = (const float*)d_in[4];
  const float* lsp  = (const float*)d_in[5];
  const float* sgp  = (const float*)d_in[6];
  float* out = (float*)d_out;
  char* ws = (char*)d_ws;

  unsigned short* Bt = (unsigned short*)(ws + 0);
  float*          P  = (float*)(ws + 11538432);
  unsigned short* Pb = (unsigned short*)(ws + 34578432);
  float*          A  = (float*)(ws + 46116864);
  float*          r  = (float*)(ws + 47443968);
  float*          tp = (float*)(ws + 47446272);
  // D (factored diag blocks, 9*64*64 fp32 = 147456 B) aliases Pb: Pb is dead
  // after gemm2, and the first lu_trsm runs strictly after gemm2 in-stream.
  float*          D  = (float*)(ws + 34578432);

  hipMemsetAsync(P, 0, (size_t)NM * NDP * sizeof(float), stream);
  prep_fused<<<PREP_BT_BLOCKS + RVEC_BLOCKS + AINIT_BLOCKS, 256, 0, stream>>>(
      F, dobs, m0p, dcov, Bt, r, A);
  gemm1<<<MT1 * SPLITK, 512, 0, stream>>>(dist, Bt, P, lsp, sgp);
  conv_p<<<NKB * 9, 256, 0, stream>>>(P, Pb);
  gemm2<<<81 * SPLITK2, 256, 0, stream>>>(Bt, Pb, A);
  for (int k = 0; k < 9; ++k){
    int nch = 8 - k;
    lu_trsm<<<2 * nch + 1, 256, 0, stream>>>(A, D, k * 64);
    if (k < 8){
      int nb = (NDP - k * 64 - 64) >> 5;
      lu_gemmk<<<nb * nb, 256, 0, stream>>>(A, k * 64);
    }
  }
  solve_ll<<<1, 576, 0, stream>>>(A, D, r, tp, out);
  mpost<<<2500, 256, 0, stream>>>(P, tp, m0p, out + 1);
}